// Round 4
// baseline (1365.567 us; speedup 1.0000x reference)
//
#include <hip/hip_runtime.h>

#define IN_DIM  512
#define HID_DIM 256
#define OUT_DIM 64
#define KPROP   5
#define ALPHA   0.1f

// ---------------- degree histogram over dst (col) ----------------
__global__ __launch_bounds__(256) void hist_kernel(const int* __restrict__ ei, int E,
                                                   int* __restrict__ counts) {
    int e = blockIdx.x * 256 + threadIdx.x;
    if (e < E) atomicAdd(&counts[ei[E + e]], 1);
}

// dinv[i] = rsqrt(deg_in(i) + 1 self loop)
__global__ __launch_bounds__(256) void dinv_kernel(const int* __restrict__ counts,
                                                   float* __restrict__ dinv, int N) {
    int i = blockIdx.x * 256 + threadIdx.x;
    if (i < N) dinv[i] = rsqrtf((float)(counts[i] + 1));
}

// ---------------- exclusive scan (3 kernels), 1024 elems / block ----------------
__global__ __launch_bounds__(256) void scan1_kernel(const int* __restrict__ counts,
                                                    int* __restrict__ indptr,
                                                    int* __restrict__ bsum, int N) {
    __shared__ int sm[256];
    int t = threadIdx.x;
    int base = blockIdx.x * 1024 + t * 4;
    int v0 = 0, v1 = 0, v2 = 0, v3 = 0;
    if (base + 0 < N) v0 = counts[base + 0];
    if (base + 1 < N) v1 = counts[base + 1];
    if (base + 2 < N) v2 = counts[base + 2];
    if (base + 3 < N) v3 = counts[base + 3];
    int s = v0 + v1 + v2 + v3;
    sm[t] = s;
    __syncthreads();
    for (int off = 1; off < 256; off <<= 1) {
        int add = 0;
        if (t >= off) add = sm[t - off];
        __syncthreads();
        if (t >= off) sm[t] += add;
        __syncthreads();
    }
    int run = sm[t] - s;  // exclusive prefix for this thread
    if (base + 0 < N) indptr[base + 0] = run; run += v0;
    if (base + 1 < N) indptr[base + 1] = run; run += v1;
    if (base + 2 < N) indptr[base + 2] = run; run += v2;
    if (base + 3 < N) indptr[base + 3] = run;
    if (t == 255) bsum[blockIdx.x] = sm[255];
}

__global__ __launch_bounds__(256) void scan2_kernel(const int* __restrict__ bsum,
                                                    int* __restrict__ boff, int nb,
                                                    int* __restrict__ indptr, int N) {
    __shared__ int sm[256];
    int t = threadIdx.x;
    int v = (t < nb) ? bsum[t] : 0;
    sm[t] = v;
    __syncthreads();
    for (int off = 1; off < 256; off <<= 1) {
        int add = 0;
        if (t >= off) add = sm[t - off];
        __syncthreads();
        if (t >= off) sm[t] += add;
        __syncthreads();
    }
    boff[t] = sm[t] - v;
    if (t == 255) indptr[N] = sm[255];  // total = E
}

__global__ __launch_bounds__(256) void scan3_kernel(int* __restrict__ indptr,
                                                    const int* __restrict__ boff, int N) {
    int i = blockIdx.x * 256 + threadIdx.x;
    if (i < N) indptr[i] += boff[i >> 10];
}

// ---------------- CSR scatter: group edges by dst ----------------
__global__ __launch_bounds__(256) void scatter_kernel(const int* __restrict__ ei, int E,
                                                      const int* __restrict__ indptr,
                                                      int* __restrict__ fill,
                                                      int* __restrict__ csr_row) {
    int e = blockIdx.x * 256 + threadIdx.x;
    if (e < E) {
        int c = ei[E + e];
        int pos = indptr[c] + atomicAdd(&fill[c], 1);
        csr_row[pos] = ei[e];
    }
}

// ---------------- fused MLP: h0 = relu(x@W1+b1)@W2 + b2 ----------------
// 32 rows/block, 256 threads. GEMM1: thread (w=t>>6, c=t&63) computes rows
// [8w..8w+8) x cols [4c..4c+4). x staged in LDS 128-k chunks; hidden kept in LDS.
__global__ __launch_bounds__(256) void mlp_kernel(const float* __restrict__ x,
                                                  const float* __restrict__ W1,
                                                  const float* __restrict__ b1,
                                                  const float* __restrict__ W2,
                                                  const float* __restrict__ b2,
                                                  float* __restrict__ h0, int N) {
    __shared__ float xs[32][128];           // 16 KB
    __shared__ float hid[32][HID_DIM + 4];  // 33.3 KB (pad)
    int t = threadIdx.x;
    int row0 = blockIdx.x * 32;
    int c4 = (t & 63) * 4;
    int r0 = (t >> 6) * 8;

    float acc[8][4];
#pragma unroll
    for (int r = 0; r < 8; ++r)
#pragma unroll
        for (int j = 0; j < 4; ++j) acc[r][j] = 0.f;

    for (int kc = 0; kc < 4; ++kc) {
        // stage x[row0..row0+32)[kc*128 .. +128) into LDS (coalesced float4)
        for (int i = t; i < 1024; i += 256) {
            int r = i >> 5;
            int kk = (i & 31) * 4;
            float4 v = make_float4(0.f, 0.f, 0.f, 0.f);
            if (row0 + r < N)
                v = *(const float4*)&x[(size_t)(row0 + r) * IN_DIM + kc * 128 + kk];
            *(float4*)&xs[r][kk] = v;
        }
        __syncthreads();
#pragma unroll 4
        for (int k = 0; k < 128; ++k) {
            float4 wv = *(const float4*)&W1[(size_t)(kc * 128 + k) * HID_DIM + c4];
#pragma unroll
            for (int r = 0; r < 8; ++r) {
                float xv = xs[r0 + r][k];
                acc[r][0] += xv * wv.x;
                acc[r][1] += xv * wv.y;
                acc[r][2] += xv * wv.z;
                acc[r][3] += xv * wv.w;
            }
        }
        __syncthreads();
    }

    float4 bv = *(const float4*)&b1[c4];
#pragma unroll
    for (int r = 0; r < 8; ++r) {
        hid[r0 + r][c4 + 0] = fmaxf(acc[r][0] + bv.x, 0.f);
        hid[r0 + r][c4 + 1] = fmaxf(acc[r][1] + bv.y, 0.f);
        hid[r0 + r][c4 + 2] = fmaxf(acc[r][2] + bv.z, 0.f);
        hid[r0 + r][c4 + 3] = fmaxf(acc[r][3] + bv.w, 0.f);
    }
    __syncthreads();

    // GEMM2: thread (w, oc=t&63) computes rows [8w..8w+8) x out col oc
    int oc = t & 63;
    float o[8];
#pragma unroll
    for (int r = 0; r < 8; ++r) o[r] = 0.f;
#pragma unroll 4
    for (int k = 0; k < HID_DIM; ++k) {
        float w2 = W2[(size_t)k * OUT_DIM + oc];
#pragma unroll
        for (int r = 0; r < 8; ++r) o[r] += hid[r0 + r][k] * w2;
    }
    float bo = b2[oc];
#pragma unroll
    for (int r = 0; r < 8; ++r) {
        int row = row0 + r0 + r;
        if (row < N) h0[(size_t)row * OUT_DIM + oc] = o[r] + bo;
    }
}

// ---------------- propagation: hn = (1-a)*(D^-1/2 (A+I) D^-1/2 h) + a*h0 ----------------
// one wave per node, lane = feature (OUT_DIM==64). CSR edge loop, no atomics.
__global__ __launch_bounds__(256) void prop_kernel(const float* __restrict__ h,
                                                   const float* __restrict__ h0,
                                                   float* __restrict__ hn,
                                                   const int* __restrict__ csr_row,
                                                   const int* __restrict__ indptr,
                                                   const float* __restrict__ dinv, int N) {
    int node = blockIdx.x * 4 + (threadIdx.x >> 6);
    if (node >= N) return;
    int lane = threadIdx.x & 63;
    int beg = indptr[node];
    int end = indptr[node + 1];
    float acc = 0.f;
    int e = beg;
    for (; e + 4 <= end; e += 4) {  // 4x unroll for load ILP
        int r0 = csr_row[e + 0];
        int r1 = csr_row[e + 1];
        int r2 = csr_row[e + 2];
        int r3 = csr_row[e + 3];
        float w0 = dinv[r0], w1 = dinv[r1], w2 = dinv[r2], w3 = dinv[r3];
        float a0 = h[(size_t)r0 * 64 + lane];
        float a1 = h[(size_t)r1 * 64 + lane];
        float a2 = h[(size_t)r2 * 64 + lane];
        float a3 = h[(size_t)r3 * 64 + lane];
        acc += w0 * a0;
        acc += w1 * a1;
        acc += w2 * a2;
        acc += w3 * a3;
    }
    for (; e < end; ++e) {
        int r = csr_row[e];
        acc += dinv[r] * h[(size_t)r * 64 + lane];
    }
    float dc = dinv[node];
    size_t base = (size_t)node * 64 + lane;
    float out = dc * (acc + dc * h[base]);  // edges + self loop
    hn[base] = (1.f - ALPHA) * out + ALPHA * h0[base];
}

// ---------------- log_softmax over 64 features (wave per node) ----------------
__global__ __launch_bounds__(256) void lsm_kernel(const float* __restrict__ h,
                                                  float* __restrict__ out, int N) {
    int node = blockIdx.x * 4 + (threadIdx.x >> 6);
    if (node >= N) return;
    int lane = threadIdx.x & 63;
    float v = h[(size_t)node * 64 + lane];
    float m = v;
    for (int off = 32; off > 0; off >>= 1) m = fmaxf(m, __shfl_xor(m, off));
    float ex = expf(v - m);
    float s = ex;
    for (int off = 32; off > 0; off >>= 1) s += __shfl_xor(s, off);
    out[(size_t)node * 64 + lane] = (v - m) - logf(s);
}

extern "C" void kernel_launch(void* const* d_in, const int* in_sizes, int n_in,
                              void* d_out, int out_size, void* d_ws, size_t ws_size,
                              hipStream_t stream) {
    const float* x  = (const float*)d_in[0];
    const int*   ei = (const int*)d_in[1];
    const float* W1 = (const float*)d_in[2];
    const float* b1 = (const float*)d_in[3];
    const float* W2 = (const float*)d_in[4];
    const float* b2 = (const float*)d_in[5];
    float* out = (float*)d_out;
    int N = in_sizes[0] / IN_DIM;
    int E = in_sizes[1] / 2;

    char* ws = (char*)d_ws;
    size_t off = 0;
    auto alloc = [&](size_t bytes) -> void* {
        void* p = ws + off;
        off += (bytes + 255) & ~(size_t)255;
        return p;
    };
    float* h0     = (float*)alloc((size_t)N * OUT_DIM * 4);
    float* hA     = (float*)alloc((size_t)N * OUT_DIM * 4);
    float* dinv   = (float*)alloc((size_t)N * 4);
    int*   counts = (int*)alloc((size_t)N * 4);
    int*   fill   = (int*)alloc((size_t)N * 4);
    int*   indptr = (int*)alloc((size_t)(N + 1) * 4);
    int*   bsum   = (int*)alloc(256 * 4);
    int*   boff   = (int*)alloc(256 * 4);
    int*   csr_row= (int*)alloc((size_t)E * 4);
    (void)ws_size; (void)n_in; (void)out_size;

    hipMemsetAsync(counts, 0, (size_t)N * 4, stream);
    hipMemsetAsync(fill, 0, (size_t)N * 4, stream);

    hist_kernel<<<(E + 255) / 256, 256, 0, stream>>>(ei, E, counts);
    dinv_kernel<<<(N + 255) / 256, 256, 0, stream>>>(counts, dinv, N);

    int nb = (N + 1023) / 1024;  // 98 <= 256
    scan1_kernel<<<nb, 256, 0, stream>>>(counts, indptr, bsum, N);
    scan2_kernel<<<1, 256, 0, stream>>>(bsum, boff, nb, indptr, N);
    scan3_kernel<<<(N + 255) / 256, 256, 0, stream>>>(indptr, boff, N);
    scatter_kernel<<<(E + 255) / 256, 256, 0, stream>>>(ei, E, indptr, fill, csr_row);

    mlp_kernel<<<(N + 31) / 32, 256, 0, stream>>>(x, W1, b1, W2, b2, h0, N);

    int pb = (N + 3) / 4;
    const float* hin = h0;
    for (int it = 0; it < KPROP; ++it) {
        float* hout = (it % 2 == 0) ? hA : out;  // out doubles as ping-pong scratch
        prop_kernel<<<pb, 256, 0, stream>>>(hin, h0, hout, csr_row, indptr, dinv, N);
        hin = hout;
    }
    // K=5 odd -> final state in hA
    lsm_kernel<<<pb, 256, 0, stream>>>(hA, out, N);
}

// Round 5
// 1078.188 us; speedup vs baseline: 1.2665x; 1.2665x over previous
//
#include <hip/hip_runtime.h>

#define IN_DIM  512
#define HID_DIM 256
#define OUT_DIM 64
#define KPROP   5
#define ALPHA   0.1f

typedef short short8v __attribute__((ext_vector_type(8)));
typedef float f32x4   __attribute__((ext_vector_type(4)));

__device__ __forceinline__ unsigned short f2bf(float f) {
    unsigned u = __builtin_bit_cast(unsigned, f);
    unsigned r = (u + 0x7FFFu + ((u >> 16) & 1u)) >> 16;
    return (unsigned short)r;
}

// ---------------- degree histogram over dst (col) ----------------
__global__ __launch_bounds__(256) void hist_kernel(const int* __restrict__ ei, int E,
                                                   int* __restrict__ counts) {
    int e = blockIdx.x * 256 + threadIdx.x;
    if (e < E) atomicAdd(&counts[ei[E + e]], 1);
}

__global__ __launch_bounds__(256) void dinv_kernel(const int* __restrict__ counts,
                                                   float* __restrict__ dinv, int N) {
    int i = blockIdx.x * 256 + threadIdx.x;
    if (i < N) dinv[i] = rsqrtf((float)(counts[i] + 1));
}

// ---------------- exclusive scan (3 kernels) ----------------
__global__ __launch_bounds__(256) void scan1_kernel(const int* __restrict__ counts,
                                                    int* __restrict__ indptr,
                                                    int* __restrict__ bsum, int N) {
    __shared__ int sm[256];
    int t = threadIdx.x;
    int base = blockIdx.x * 1024 + t * 4;
    int v0 = 0, v1 = 0, v2 = 0, v3 = 0;
    if (base + 0 < N) v0 = counts[base + 0];
    if (base + 1 < N) v1 = counts[base + 1];
    if (base + 2 < N) v2 = counts[base + 2];
    if (base + 3 < N) v3 = counts[base + 3];
    int s = v0 + v1 + v2 + v3;
    sm[t] = s;
    __syncthreads();
    for (int off = 1; off < 256; off <<= 1) {
        int add = 0;
        if (t >= off) add = sm[t - off];
        __syncthreads();
        if (t >= off) sm[t] += add;
        __syncthreads();
    }
    int run = sm[t] - s;
    if (base + 0 < N) indptr[base + 0] = run; run += v0;
    if (base + 1 < N) indptr[base + 1] = run; run += v1;
    if (base + 2 < N) indptr[base + 2] = run; run += v2;
    if (base + 3 < N) indptr[base + 3] = run;
    if (t == 255) bsum[blockIdx.x] = sm[255];
}

__global__ __launch_bounds__(256) void scan2_kernel(const int* __restrict__ bsum,
                                                    int* __restrict__ boff, int nb,
                                                    int* __restrict__ indptr, int N) {
    __shared__ int sm[256];
    int t = threadIdx.x;
    int v = (t < nb) ? bsum[t] : 0;
    sm[t] = v;
    __syncthreads();
    for (int off = 1; off < 256; off <<= 1) {
        int add = 0;
        if (t >= off) add = sm[t - off];
        __syncthreads();
        if (t >= off) sm[t] += add;
        __syncthreads();
    }
    boff[t] = sm[t] - v;
    if (t == 255) indptr[N] = sm[255];
}

__global__ __launch_bounds__(256) void scan3_kernel(int* __restrict__ indptr,
                                                    const int* __restrict__ boff, int N) {
    int i = blockIdx.x * 256 + threadIdx.x;
    if (i < N) indptr[i] += boff[i >> 10];
}

// ---------------- CSR scatter ----------------
__global__ __launch_bounds__(256) void scatter_kernel(const int* __restrict__ ei, int E,
                                                      const int* __restrict__ indptr,
                                                      int* __restrict__ fill,
                                                      int* __restrict__ csr_row) {
    int e = blockIdx.x * 256 + threadIdx.x;
    if (e < E) {
        int c = ei[E + e];
        int pos = indptr[c] + atomicAdd(&fill[c], 1);
        csr_row[pos] = ei[e];
    }
}

// ---------------- weight prep: bf16 + transpose into frag-friendly layouts ----------------
// w1p[q][c][j] = bf16(W1[q*64+j][c])   q=K-chunk(8), c=hid col(256), j=k within chunk(64)
__global__ __launch_bounds__(256) void prep_w1_kernel(const float* __restrict__ W1,
                                                      unsigned short* __restrict__ w1p) {
    int idx = blockIdx.x * 256 + threadIdx.x;  // 0..131071
    int q = idx >> 14;
    int rem = idx & 16383;
    int c = rem >> 6, j = rem & 63;
    w1p[idx] = f2bf(W1[(size_t)(q * 64 + j) * HID_DIM + c]);
}

// w2p[c][k] = bf16(W2[k][c])   c=out col(64), k(256)
__global__ __launch_bounds__(256) void prep_w2_kernel(const float* __restrict__ W2,
                                                      unsigned short* __restrict__ w2p) {
    int idx = blockIdx.x * 256 + threadIdx.x;  // 0..16383
    int c = idx >> 8, k = idx & 255;
    w2p[idx] = f2bf(W2[(size_t)k * OUT_DIM + c]);
}

// ---------------- MFMA MLP: h0 = relu(x@W1+b1)@W2 + b2 (bf16 in, fp32 accum) ----------------
// 64 rows/block, 4 waves; wave w owns rows [16w,16w+16).
// GEMM1: 16 col-tiles of 16x16, K=512 in 8 chunks of 64. GEMM2: 4 col-tiles, K=256.
// Frag layout (m89-verified): A row=l&15, k=8*(l>>4)+j ; B col=l&15 ; D row=4*(l>>4)+i, col=l&15.
struct __align__(16) MlpSmem {
    union {
        struct {
            unsigned short xs[64][72];    // x chunk, +8 pad (2-way banks)
            unsigned short ws[256][72];   // W1 chunk
        };
        unsigned short w2s[64][264];      // GEMM2 weights (phase 2)
    };
    unsigned short hid[64][264];          // hidden acts bf16, +8 pad
};

__global__ __launch_bounds__(256) void mlp_mfma_kernel(const float* __restrict__ x,
                                                       const unsigned short* __restrict__ w1p,
                                                       const float* __restrict__ b1,
                                                       const unsigned short* __restrict__ w2p,
                                                       const float* __restrict__ b2,
                                                       float* __restrict__ h0, int N) {
    __shared__ MlpSmem sm;
    int t = threadIdx.x;
    int w = t >> 6, l = t & 63;
    int l15 = l & 15, l4 = l >> 4;
    int wr0 = w * 16;
    int row0 = blockIdx.x * 64;

    f32x4 acc[16];
#pragma unroll
    for (int i = 0; i < 16; ++i) acc[i] = (f32x4){0.f, 0.f, 0.f, 0.f};

    for (int q = 0; q < 8; ++q) {
        // stage x[row0..+64)[q*64..+64) -> bf16 LDS (coalesced float4)
#pragma unroll
        for (int i = 0; i < 4; ++i) {
            int e = t * 4 + i * 1024;
            int r = e >> 6, j = e & 63;
            float4 v = make_float4(0.f, 0.f, 0.f, 0.f);
            if (row0 + r < N)
                v = *(const float4*)&x[(size_t)(row0 + r) * IN_DIM + q * 64 + j];
            unsigned u0 = (unsigned)f2bf(v.x) | ((unsigned)f2bf(v.y) << 16);
            unsigned u1 = (unsigned)f2bf(v.z) | ((unsigned)f2bf(v.w) << 16);
            *(uint2*)&sm.xs[r][j] = make_uint2(u0, u1);
        }
        // stage W1 chunk (pre-transposed, contiguous 32KB, coalesced uint4)
        const unsigned short* src = w1p + q * 16384;
#pragma unroll
        for (int i = 0; i < 8; ++i) {
            int e = t * 8 + i * 2048;
            int c = e >> 6, j = e & 63;
            *(uint4*)&sm.ws[c][j] = *(const uint4*)&src[e];
        }
        __syncthreads();
#pragma unroll
        for (int s = 0; s < 2; ++s) {
            short8v a = *(const short8v*)&sm.xs[wr0 + l15][s * 32 + l4 * 8];
#pragma unroll
            for (int tc = 0; tc < 16; ++tc) {
                short8v b = *(const short8v*)&sm.ws[tc * 16 + l15][s * 32 + l4 * 8];
                acc[tc] = __builtin_amdgcn_mfma_f32_16x16x32_bf16(a, b, acc[tc], 0, 0, 0);
            }
        }
        __syncthreads();
    }

    // epilogue1: bias + relu -> hid (bf16), own row band
#pragma unroll
    for (int tc = 0; tc < 16; ++tc) {
        float bv = b1[tc * 16 + l15];
#pragma unroll
        for (int i = 0; i < 4; ++i) {
            float v = fmaxf(acc[tc][i] + bv, 0.f);
            sm.hid[wr0 + l4 * 4 + i][tc * 16 + l15] = f2bf(v);
        }
    }
    // stage W2 (contiguous 32KB; overwrites xs/ws — all waves past last compute barrier)
#pragma unroll
    for (int i = 0; i < 8; ++i) {
        int e = t * 8 + i * 2048;
        int c = e >> 8, k = e & 255;
        *(uint4*)&sm.w2s[c][k] = *(const uint4*)&w2p[e];
    }
    __syncthreads();

    f32x4 acc2[4];
#pragma unroll
    for (int i = 0; i < 4; ++i) acc2[i] = (f32x4){0.f, 0.f, 0.f, 0.f};
#pragma unroll
    for (int s = 0; s < 8; ++s) {
        short8v a = *(const short8v*)&sm.hid[wr0 + l15][s * 32 + l4 * 8];
#pragma unroll
        for (int tc = 0; tc < 4; ++tc) {
            short8v b = *(const short8v*)&sm.w2s[tc * 16 + l15][s * 32 + l4 * 8];
            acc2[tc] = __builtin_amdgcn_mfma_f32_16x16x32_bf16(a, b, acc2[tc], 0, 0, 0);
        }
    }
#pragma unroll
    for (int tc = 0; tc < 4; ++tc) {
        float bv = b2[tc * 16 + l15];
#pragma unroll
        for (int i = 0; i < 4; ++i) {
            int row = row0 + wr0 + l4 * 4 + i;
            if (row < N) h0[(size_t)row * OUT_DIM + tc * 16 + l15] = acc2[tc][i] + bv;
        }
    }
}

// ---------------- propagation (unchanged, fp32) ----------------
__global__ __launch_bounds__(256) void prop_kernel(const float* __restrict__ h,
                                                   const float* __restrict__ h0,
                                                   float* __restrict__ hn,
                                                   const int* __restrict__ csr_row,
                                                   const int* __restrict__ indptr,
                                                   const float* __restrict__ dinv, int N) {
    int node = blockIdx.x * 4 + (threadIdx.x >> 6);
    if (node >= N) return;
    int lane = threadIdx.x & 63;
    int beg = indptr[node];
    int end = indptr[node + 1];
    float acc = 0.f;
    int e = beg;
    for (; e + 4 <= end; e += 4) {
        int r0 = csr_row[e + 0];
        int r1 = csr_row[e + 1];
        int r2 = csr_row[e + 2];
        int r3 = csr_row[e + 3];
        float w0 = dinv[r0], w1 = dinv[r1], w2 = dinv[r2], w3 = dinv[r3];
        float a0 = h[(size_t)r0 * 64 + lane];
        float a1 = h[(size_t)r1 * 64 + lane];
        float a2 = h[(size_t)r2 * 64 + lane];
        float a3 = h[(size_t)r3 * 64 + lane];
        acc += w0 * a0;
        acc += w1 * a1;
        acc += w2 * a2;
        acc += w3 * a3;
    }
    for (; e < end; ++e) {
        int r = csr_row[e];
        acc += dinv[r] * h[(size_t)r * 64 + lane];
    }
    float dc = dinv[node];
    size_t base = (size_t)node * 64 + lane;
    float out = dc * (acc + dc * h[base]);
    hn[base] = (1.f - ALPHA) * out + ALPHA * h0[base];
}

// ---------------- log_softmax ----------------
__global__ __launch_bounds__(256) void lsm_kernel(const float* __restrict__ h,
                                                  float* __restrict__ out, int N) {
    int node = blockIdx.x * 4 + (threadIdx.x >> 6);
    if (node >= N) return;
    int lane = threadIdx.x & 63;
    float v = h[(size_t)node * 64 + lane];
    float m = v;
    for (int off = 32; off > 0; off >>= 1) m = fmaxf(m, __shfl_xor(m, off));
    float ex = expf(v - m);
    float s = ex;
    for (int off = 32; off > 0; off >>= 1) s += __shfl_xor(s, off);
    out[(size_t)node * 64 + lane] = (v - m) - logf(s);
}

extern "C" void kernel_launch(void* const* d_in, const int* in_sizes, int n_in,
                              void* d_out, int out_size, void* d_ws, size_t ws_size,
                              hipStream_t stream) {
    const float* x  = (const float*)d_in[0];
    const int*   ei = (const int*)d_in[1];
    const float* W1 = (const float*)d_in[2];
    const float* b1 = (const float*)d_in[3];
    const float* W2 = (const float*)d_in[4];
    const float* b2 = (const float*)d_in[5];
    float* out = (float*)d_out;
    int N = in_sizes[0] / IN_DIM;
    int E = in_sizes[1] / 2;

    char* ws = (char*)d_ws;
    size_t off = 0;
    auto alloc = [&](size_t bytes) -> void* {
        void* p = ws + off;
        off += (bytes + 255) & ~(size_t)255;
        return p;
    };
    float* h0     = (float*)alloc((size_t)N * OUT_DIM * 4);
    float* hA     = (float*)alloc((size_t)N * OUT_DIM * 4);
    float* dinv   = (float*)alloc((size_t)N * 4);
    int*   counts = (int*)alloc((size_t)N * 4);
    int*   fill   = (int*)alloc((size_t)N * 4);
    int*   indptr = (int*)alloc((size_t)(N + 1) * 4);
    int*   bsum   = (int*)alloc(256 * 4);
    int*   boff   = (int*)alloc(256 * 4);
    int*   csr_row= (int*)alloc((size_t)E * 4);
    unsigned short* w1p = (unsigned short*)alloc((size_t)IN_DIM * HID_DIM * 2);
    unsigned short* w2p = (unsigned short*)alloc((size_t)HID_DIM * OUT_DIM * 2);
    (void)ws_size; (void)n_in; (void)out_size;

    hipMemsetAsync(counts, 0, (size_t)N * 4, stream);
    hipMemsetAsync(fill, 0, (size_t)N * 4, stream);

    prep_w1_kernel<<<(IN_DIM * HID_DIM) / 256, 256, 0, stream>>>(W1, w1p);
    prep_w2_kernel<<<(HID_DIM * OUT_DIM) / 256, 256, 0, stream>>>(W2, w2p);

    hist_kernel<<<(E + 255) / 256, 256, 0, stream>>>(ei, E, counts);
    dinv_kernel<<<(N + 255) / 256, 256, 0, stream>>>(counts, dinv, N);

    int nb = (N + 1023) / 1024;
    scan1_kernel<<<nb, 256, 0, stream>>>(counts, indptr, bsum, N);
    scan2_kernel<<<1, 256, 0, stream>>>(bsum, boff, nb, indptr, N);
    scan3_kernel<<<(N + 255) / 256, 256, 0, stream>>>(indptr, boff, N);
    scatter_kernel<<<(E + 255) / 256, 256, 0, stream>>>(ei, E, indptr, fill, csr_row);

    mlp_mfma_kernel<<<(N + 63) / 64, 256, 0, stream>>>(x, w1p, b1, w2p, b2, h0, N);

    int pb = (N + 3) / 4;
    const float* hin = h0;
    for (int it = 0; it < KPROP; ++it) {
        float* hout = (it % 2 == 0) ? hA : out;
        prop_kernel<<<pb, 256, 0, stream>>>(hin, h0, hout, csr_row, indptr, dinv, N);
        hin = hout;
    }
    lsm_kernel<<<pb, 256, 0, stream>>>(hA, out, N);
}

// Round 6
// 838.038 us; speedup vs baseline: 1.6295x; 1.2866x over previous
//
#include <hip/hip_runtime.h>

#define IN_DIM  512
#define HID_DIM 256
#define OUT_DIM 64
#define KPROP   5
#define ALPHA   0.1f

typedef short short8v __attribute__((ext_vector_type(8)));
typedef float f32x4   __attribute__((ext_vector_type(4)));

__device__ __forceinline__ unsigned short f2bf(float f) {
    unsigned u = __builtin_bit_cast(unsigned, f);
    unsigned r = (u + 0x7FFFu + ((u >> 16) & 1u)) >> 16;
    return (unsigned short)r;
}
__device__ __forceinline__ float bflo(unsigned v) { return __builtin_bit_cast(float, v << 16); }
__device__ __forceinline__ float bfhi(unsigned v) { return __builtin_bit_cast(float, v & 0xffff0000u); }

// ---------------- degree histogram over dst (col) ----------------
__global__ __launch_bounds__(256) void hist_kernel(const int* __restrict__ ei, int E,
                                                   int* __restrict__ counts) {
    int e = blockIdx.x * 256 + threadIdx.x;
    if (e < E) atomicAdd(&counts[ei[E + e]], 1);
}

__global__ __launch_bounds__(256) void dinv_kernel(const int* __restrict__ counts,
                                                   float* __restrict__ dinv, int N) {
    int i = blockIdx.x * 256 + threadIdx.x;
    if (i < N) dinv[i] = rsqrtf((float)(counts[i] + 1));
}

// ---------------- exclusive scan (3 kernels) ----------------
__global__ __launch_bounds__(256) void scan1_kernel(const int* __restrict__ counts,
                                                    int* __restrict__ indptr,
                                                    int* __restrict__ bsum, int N) {
    __shared__ int sm[256];
    int t = threadIdx.x;
    int base = blockIdx.x * 1024 + t * 4;
    int v0 = 0, v1 = 0, v2 = 0, v3 = 0;
    if (base + 0 < N) v0 = counts[base + 0];
    if (base + 1 < N) v1 = counts[base + 1];
    if (base + 2 < N) v2 = counts[base + 2];
    if (base + 3 < N) v3 = counts[base + 3];
    int s = v0 + v1 + v2 + v3;
    sm[t] = s;
    __syncthreads();
    for (int off = 1; off < 256; off <<= 1) {
        int add = 0;
        if (t >= off) add = sm[t - off];
        __syncthreads();
        if (t >= off) sm[t] += add;
        __syncthreads();
    }
    int run = sm[t] - s;
    if (base + 0 < N) indptr[base + 0] = run; run += v0;
    if (base + 1 < N) indptr[base + 1] = run; run += v1;
    if (base + 2 < N) indptr[base + 2] = run; run += v2;
    if (base + 3 < N) indptr[base + 3] = run;
    if (t == 255) bsum[blockIdx.x] = sm[255];
}

__global__ __launch_bounds__(256) void scan2_kernel(const int* __restrict__ bsum,
                                                    int* __restrict__ boff, int nb,
                                                    int* __restrict__ indptr, int N) {
    __shared__ int sm[256];
    int t = threadIdx.x;
    int v = (t < nb) ? bsum[t] : 0;
    sm[t] = v;
    __syncthreads();
    for (int off = 1; off < 256; off <<= 1) {
        int add = 0;
        if (t >= off) add = sm[t - off];
        __syncthreads();
        if (t >= off) sm[t] += add;
        __syncthreads();
    }
    boff[t] = sm[t] - v;
    if (t == 255) indptr[N] = sm[255];
}

__global__ __launch_bounds__(256) void scan3_kernel(int* __restrict__ indptr,
                                                    const int* __restrict__ boff, int N) {
    int i = blockIdx.x * 256 + threadIdx.x;
    if (i < N) indptr[i] += boff[i >> 10];
}

// ---------------- CSR scatter ----------------
__global__ __launch_bounds__(256) void scatter_kernel(const int* __restrict__ ei, int E,
                                                      const int* __restrict__ indptr,
                                                      int* __restrict__ fill,
                                                      int* __restrict__ csr_row) {
    int e = blockIdx.x * 256 + threadIdx.x;
    if (e < E) {
        int c = ei[E + e];
        int pos = indptr[c] + atomicAdd(&fill[c], 1);
        csr_row[pos] = ei[e];
    }
}

// ---------------- weight prep ----------------
__global__ __launch_bounds__(256) void prep_w1_kernel(const float* __restrict__ W1,
                                                      unsigned short* __restrict__ w1p) {
    int idx = blockIdx.x * 256 + threadIdx.x;
    int q = idx >> 14;
    int rem = idx & 16383;
    int c = rem >> 6, j = rem & 63;
    w1p[idx] = f2bf(W1[(size_t)(q * 64 + j) * HID_DIM + c]);
}

__global__ __launch_bounds__(256) void prep_w2_kernel(const float* __restrict__ W2,
                                                      unsigned short* __restrict__ w2p) {
    int idx = blockIdx.x * 256 + threadIdx.x;
    int c = idx >> 8, k = idx & 255;
    w2p[idx] = f2bf(W2[(size_t)k * OUT_DIM + c]);
}

// ---------------- MFMA MLP (unchanged from round 5) ----------------
struct __align__(16) MlpSmem {
    union {
        struct {
            unsigned short xs[64][72];
            unsigned short ws[256][72];
        };
        unsigned short w2s[64][264];
    };
    unsigned short hid[64][264];
};

__global__ __launch_bounds__(256) void mlp_mfma_kernel(const float* __restrict__ x,
                                                       const unsigned short* __restrict__ w1p,
                                                       const float* __restrict__ b1,
                                                       const unsigned short* __restrict__ w2p,
                                                       const float* __restrict__ b2,
                                                       float* __restrict__ h0, int N) {
    __shared__ MlpSmem sm;
    int t = threadIdx.x;
    int w = t >> 6, l = t & 63;
    int l15 = l & 15, l4 = l >> 4;
    int wr0 = w * 16;
    int row0 = blockIdx.x * 64;

    f32x4 acc[16];
#pragma unroll
    for (int i = 0; i < 16; ++i) acc[i] = (f32x4){0.f, 0.f, 0.f, 0.f};

    for (int q = 0; q < 8; ++q) {
#pragma unroll
        for (int i = 0; i < 4; ++i) {
            int e = t * 4 + i * 1024;
            int r = e >> 6, j = e & 63;
            float4 v = make_float4(0.f, 0.f, 0.f, 0.f);
            if (row0 + r < N)
                v = *(const float4*)&x[(size_t)(row0 + r) * IN_DIM + q * 64 + j];
            unsigned u0 = (unsigned)f2bf(v.x) | ((unsigned)f2bf(v.y) << 16);
            unsigned u1 = (unsigned)f2bf(v.z) | ((unsigned)f2bf(v.w) << 16);
            *(uint2*)&sm.xs[r][j] = make_uint2(u0, u1);
        }
        const unsigned short* src = w1p + q * 16384;
#pragma unroll
        for (int i = 0; i < 8; ++i) {
            int e = t * 8 + i * 2048;
            int c = e >> 6, j = e & 63;
            *(uint4*)&sm.ws[c][j] = *(const uint4*)&src[e];
        }
        __syncthreads();
#pragma unroll
        for (int s = 0; s < 2; ++s) {
            short8v a = *(const short8v*)&sm.xs[wr0 + l15][s * 32 + l4 * 8];
#pragma unroll
            for (int tc = 0; tc < 16; ++tc) {
                short8v b = *(const short8v*)&sm.ws[tc * 16 + l15][s * 32 + l4 * 8];
                acc[tc] = __builtin_amdgcn_mfma_f32_16x16x32_bf16(a, b, acc[tc], 0, 0, 0);
            }
        }
        __syncthreads();
    }

#pragma unroll
    for (int tc = 0; tc < 16; ++tc) {
        float bv = b1[tc * 16 + l15];
#pragma unroll
        for (int i = 0; i < 4; ++i) {
            float v = fmaxf(acc[tc][i] + bv, 0.f);
            sm.hid[wr0 + l4 * 4 + i][tc * 16 + l15] = f2bf(v);
        }
    }
#pragma unroll
    for (int i = 0; i < 8; ++i) {
        int e = t * 8 + i * 2048;
        int c = e >> 8, k = e & 255;
        *(uint4*)&sm.w2s[c][k] = *(const uint4*)&w2p[e];
    }
    __syncthreads();

    f32x4 acc2[4];
#pragma unroll
    for (int i = 0; i < 4; ++i) acc2[i] = (f32x4){0.f, 0.f, 0.f, 0.f};
#pragma unroll
    for (int s = 0; s < 8; ++s) {
        short8v a = *(const short8v*)&sm.hid[wr0 + l15][s * 32 + l4 * 8];
#pragma unroll
        for (int tc = 0; tc < 4; ++tc) {
            short8v b = *(const short8v*)&sm.w2s[tc * 16 + l15][s * 32 + l4 * 8];
            acc2[tc] = __builtin_amdgcn_mfma_f32_16x16x32_bf16(a, b, acc2[tc], 0, 0, 0);
        }
    }
#pragma unroll
    for (int tc = 0; tc < 4; ++tc) {
        float bv = b2[tc * 16 + l15];
#pragma unroll
        for (int i = 0; i < 4; ++i) {
            int row = row0 + wr0 + l4 * 4 + i;
            if (row < N) h0[(size_t)row * OUT_DIM + tc * 16 + l15] = acc2[tc][i] + bv;
        }
    }
}

// ---------------- hs init: hs[i] = bf16(dinv[i] * h0[i]) ----------------
__global__ __launch_bounds__(256) void hs_init_kernel(const float* __restrict__ h0,
                                                      const float* __restrict__ dinv,
                                                      unsigned short* __restrict__ hs, int N) {
    int idx = blockIdx.x * 256 + threadIdx.x;  // one per 4 features
    if (idx >= N * 16) return;
    int node = idx >> 4;
    int j = (idx & 15) * 4;
    float d = dinv[node];
    float4 v = *(const float4*)&h0[(size_t)node * 64 + j];
    ushort4 o;
    o.x = f2bf(d * v.x);
    o.y = f2bf(d * v.y);
    o.z = f2bf(d * v.z);
    o.w = f2bf(d * v.w);
    *(ushort4*)&hs[(size_t)node * 64 + j] = o;
}

// ---------------- propagation, bf16 prescaled messages ----------------
// wave per node; lane l: half=l>>5 processes alternating edges, li=l&31 owns
// features {2li, 2li+1} (one uint = 2 bf16 per row gather, 128B/row coalesced).
// hs[r] = dinv[r]*h[r] (bf16). out = (1-a)*dinv_c*(sum_r hs[r] + hs[c]) + a*h0[c].
// Writes next iter's prescaled buffer (bf16) or, if last, fp32 result.
__global__ __launch_bounds__(256) void prop_bf16_kernel(const unsigned short* __restrict__ hs,
                                                        const float* __restrict__ h0,
                                                        const float* __restrict__ dinv,
                                                        const int* __restrict__ csr_row,
                                                        const int* __restrict__ indptr,
                                                        unsigned short* __restrict__ hs_out,
                                                        float* __restrict__ hfin,
                                                        int last, int N) {
    int node = blockIdx.x * 4 + (threadIdx.x >> 6);
    if (node >= N) return;
    int l = threadIdx.x & 63;
    int half = l >> 5, li = l & 31;
    const unsigned* hs32 = (const unsigned*)hs;
    int beg = indptr[node], end = indptr[node + 1];
    float a0 = 0.f, a1 = 0.f;
    int e = beg;
    for (; e + 8 <= end; e += 8) {  // 8 edges per trip (4 per half)
        int r0 = csr_row[e + 0 + half];
        int r1 = csr_row[e + 2 + half];
        int r2 = csr_row[e + 4 + half];
        int r3 = csr_row[e + 6 + half];
        unsigned v0 = hs32[(size_t)r0 * 32 + li];
        unsigned v1 = hs32[(size_t)r1 * 32 + li];
        unsigned v2 = hs32[(size_t)r2 * 32 + li];
        unsigned v3 = hs32[(size_t)r3 * 32 + li];
        a0 += bflo(v0); a1 += bfhi(v0);
        a0 += bflo(v1); a1 += bfhi(v1);
        a0 += bflo(v2); a1 += bfhi(v2);
        a0 += bflo(v3); a1 += bfhi(v3);
    }
    for (; e + 2 <= end; e += 2) {
        int r = csr_row[e + half];
        unsigned v = hs32[(size_t)r * 32 + li];
        a0 += bflo(v); a1 += bfhi(v);
    }
    if (e < end && half == 0) {  // odd leftover edge: half 0 only
        int r = csr_row[e];
        unsigned v = hs32[(size_t)r * 32 + li];
        a0 += bflo(v); a1 += bfhi(v);
    }
    a0 += __shfl_xor(a0, 32);
    a1 += __shfl_xor(a1, 32);
    unsigned vs = hs32[(size_t)node * 32 + li];  // self loop
    a0 += bflo(vs);
    a1 += bfhi(vs);
    float dcn = dinv[node];
    float2 z = *(const float2*)&h0[(size_t)node * 64 + li * 2];
    float o0 = (1.0f - ALPHA) * (dcn * a0) + ALPHA * z.x;
    float o1 = (1.0f - ALPHA) * (dcn * a1) + ALPHA * z.y;
    if (half == 0) {
        if (last) {
            *(float2*)&hfin[(size_t)node * 64 + li * 2] = make_float2(o0, o1);
        } else {
            unsigned p = (unsigned)f2bf(dcn * o0) | ((unsigned)f2bf(dcn * o1) << 16);
            ((unsigned*)hs_out)[(size_t)node * 32 + li] = p;
        }
    }
}

// ---------------- log_softmax (in-place safe) ----------------
__global__ __launch_bounds__(256) void lsm_kernel(const float* __restrict__ h,
                                                  float* __restrict__ out, int N) {
    int node = blockIdx.x * 4 + (threadIdx.x >> 6);
    if (node >= N) return;
    int lane = threadIdx.x & 63;
    float v = h[(size_t)node * 64 + lane];
    float m = v;
    for (int off = 32; off > 0; off >>= 1) m = fmaxf(m, __shfl_xor(m, off));
    float ex = expf(v - m);
    float s = ex;
    for (int off = 32; off > 0; off >>= 1) s += __shfl_xor(s, off);
    out[(size_t)node * 64 + lane] = (v - m) - logf(s);
}

extern "C" void kernel_launch(void* const* d_in, const int* in_sizes, int n_in,
                              void* d_out, int out_size, void* d_ws, size_t ws_size,
                              hipStream_t stream) {
    const float* x  = (const float*)d_in[0];
    const int*   ei = (const int*)d_in[1];
    const float* W1 = (const float*)d_in[2];
    const float* b1 = (const float*)d_in[3];
    const float* W2 = (const float*)d_in[4];
    const float* b2 = (const float*)d_in[5];
    float* out = (float*)d_out;
    int N = in_sizes[0] / IN_DIM;
    int E = in_sizes[1] / 2;

    char* ws = (char*)d_ws;
    size_t off = 0;
    auto alloc = [&](size_t bytes) -> void* {
        void* p = ws + off;
        off += (bytes + 255) & ~(size_t)255;
        return p;
    };
    float* h0     = (float*)alloc((size_t)N * OUT_DIM * 4);
    float* dinv   = (float*)alloc((size_t)N * 4);
    int*   counts = (int*)alloc((size_t)N * 4);
    int*   fill   = (int*)alloc((size_t)N * 4);
    int*   indptr = (int*)alloc((size_t)(N + 1) * 4);
    int*   bsum   = (int*)alloc(256 * 4);
    int*   boff   = (int*)alloc(256 * 4);
    int*   csr_row= (int*)alloc((size_t)E * 4);
    unsigned short* w1p = (unsigned short*)alloc((size_t)IN_DIM * HID_DIM * 2);
    unsigned short* w2p = (unsigned short*)alloc((size_t)HID_DIM * OUT_DIM * 2);
    unsigned short* hsA = (unsigned short*)alloc((size_t)N * OUT_DIM * 2);
    unsigned short* hsB = (unsigned short*)alloc((size_t)N * OUT_DIM * 2);
    (void)ws_size; (void)n_in; (void)out_size;

    hipMemsetAsync(counts, 0, (size_t)N * 4, stream);
    hipMemsetAsync(fill, 0, (size_t)N * 4, stream);

    prep_w1_kernel<<<(IN_DIM * HID_DIM) / 256, 256, 0, stream>>>(W1, w1p);
    prep_w2_kernel<<<(HID_DIM * OUT_DIM) / 256, 256, 0, stream>>>(W2, w2p);

    hist_kernel<<<(E + 255) / 256, 256, 0, stream>>>(ei, E, counts);
    dinv_kernel<<<(N + 255) / 256, 256, 0, stream>>>(counts, dinv, N);

    int nb = (N + 1023) / 1024;
    scan1_kernel<<<nb, 256, 0, stream>>>(counts, indptr, bsum, N);
    scan2_kernel<<<1, 256, 0, stream>>>(bsum, boff, nb, indptr, N);
    scan3_kernel<<<(N + 255) / 256, 256, 0, stream>>>(indptr, boff, N);
    scatter_kernel<<<(E + 255) / 256, 256, 0, stream>>>(ei, E, indptr, fill, csr_row);

    mlp_mfma_kernel<<<(N + 63) / 64, 256, 0, stream>>>(x, w1p, b1, w2p, b2, h0, N);

    hs_init_kernel<<<(N * 16 + 255) / 256, 256, 0, stream>>>(h0, dinv, hsA, N);

    int pb = (N + 3) / 4;
    for (int it = 0; it < KPROP; ++it) {
        const unsigned short* hin = (it % 2 == 0) ? hsA : hsB;
        unsigned short* hout = (it % 2 == 0) ? hsB : hsA;
        int last = (it == KPROP - 1) ? 1 : 0;
        prop_bf16_kernel<<<pb, 256, 0, stream>>>(hin, h0, dinv, csr_row, indptr,
                                                 hout, out, last, N);
    }
    lsm_kernel<<<pb, 256, 0, stream>>>(out, out, N);
}